// Round 10
// baseline (58.873 us; speedup 1.0000x reference)
//
#include <hip/hip_runtime.h>

// Problem constants
#define B_ 4096
#define S_ 32
#define K_ 1024
#define D_ 128
constexpr float DECAY = 0.99f;
constexpr float OMD   = 0.01f;     // 1 - decay
constexpr float EPS   = 1e-5f;

typedef float f4 __attribute__((ext_vector_type(4)));

// Single kernel, 4096 blocks x 256 threads, role-split by blockIdx bit 3:
//   role 0 (2048 blocks): z_q gather   (write-heavy)
//   role 1 (2048 blocks): 16-bin hist from strided idx reads + n[s] closed
//                         form + fused EMA/Laplace (read-heavy)
// Both halves co-resident -> mixed read/write HBM traffic; one launch.
// sub%8 == blockIdx%8, so s = sub&31 keeps s%8 == XCD (round-robin %8):
// each s's 512KB emb slice stays pinned in one XCD's L2 for both roles.
// NT stores for the 101MB of write-once outputs (R9 A/B: NT beats plain by
// 2.5us -- plain stores pay write-allocate reads).
__global__ void __launch_bounds__(256)
fused_kernel(const int* __restrict__ idx,
             const float* __restrict__ emb,
             const float* __restrict__ ecs_in,
             const float* __restrict__ ema_w,
             float* __restrict__ z_q,
             float* __restrict__ new_ecs_out,
             float* __restrict__ new_ema_w_out,
             float* __restrict__ new_emb_out) {
    const int role = (blockIdx.x >> 3) & 1;
    const int sub  = (int)(((blockIdx.x >> 4) << 3) | (blockIdx.x & 7)); // [0,2048)
    const int t    = threadIdx.x;
    const int s    = sub & (S_ - 1);

    __shared__ int   hist[16];
    __shared__ float red[4];
    __shared__ float n_sh;

    if (role == 0) {
        // ---- Gather half: 64 rows/block, 8 idx prefetched -> 8 gathers in flight.
        const int chunk = sub >> 5;          // [0, 64)
        const int g     = t >> 5;            // row group 0..7
        const int lane  = t & 31;
        int kk[8];
#pragma unroll
        for (int it = 0; it < 8; ++it) {
            const int b = chunk * 64 + it * 8 + g;
            kk[it] = idx[b * S_ + s];        // coalesced-ish broadcast load
        }
#pragma unroll
        for (int it = 0; it < 8; ++it) {
            const int b = chunk * 64 + it * 8 + g;
            const f4 val =
                reinterpret_cast<const f4*>(emb)[((size_t)s * K_ + kk[it]) * 32 + lane];
            __builtin_nontemporal_store(
                val, reinterpret_cast<f4*>(z_q) + ((size_t)b * S_ + s) * 32 + lane);
        }
    } else {
        // ---- Hist + EMA half: k-chunk c of 16 bins for state s.
        const int c     = sub >> 5;          // [0, 64)
        const int kbase = c * 16;
        if (t < 16) hist[t] = 0;
        __syncthreads();

        // Histogram: scan column s of idx (stride 128B, L2-resident 512KB).
        // All 16 loads issued first for ILP.
        int kv[16];
#pragma unroll
        for (int j = 0; j < 16; ++j)
            kv[j] = idx[(j * 256 + t) * S_ + s];
#pragma unroll
        for (int j = 0; j < 16; ++j) {
            const unsigned u = (unsigned)kv[j] - (unsigned)kbase;
            if (u < 16u) atomicAdd(&hist[u], 1);
        }

        // n[s] via closed form: n = DECAY*rowsum(ecs[s]) + OMD*B
        // (sum_k counts[s,k] == B exactly).
        const f4 v = reinterpret_cast<const f4*>(ecs_in + s * K_)[t];
        float local = v.x + v.y + v.z + v.w;
#pragma unroll
        for (int off = 1; off < 64; off <<= 1) local += __shfl_xor(local, off);
        if ((t & 63) == 0) red[t >> 6] = local;
        __syncthreads();                     // also publishes hist atomics
        if (t == 0)
            n_sh = DECAY * (red[0] + red[1] + red[2] + red[3]) + OMD * (float)B_;
        __syncthreads();
        const float n = n_sh;
        const float denom_inv = 1.0f / (n + (float)K_ * EPS);

        // Fused EMA elementwise: 512 f4 per block (16 bins x 32 f4).
        // dw == counts*emb algebraically (z_q rows are codebook rows).
        const size_t base = ((size_t)s * K_ + kbase) * 32;   // f4 base
#pragma unroll
        for (int it = 0; it < 2; ++it) {
            const int    off = it * 256 + t;
            const int    ub  = off >> 5;     // local bin [0, 16)
            const size_t e   = base + off;   // global f4 index
            const int    sk  = (int)(e >> 5);
            const float ccount = (float)hist[ub];
            const float ne = DECAY * ecs_in[sk] + OMD * ccount;
            const float cs = (ne + EPS) * denom_inv * n;
            if ((off & 31) == 0) new_ecs_out[sk] = ne;

            const f4 w  = reinterpret_cast<const f4*>(ema_w)[e];
            const f4 em = reinterpret_cast<const f4*>(emb)[e];
            f4 nw;
            nw.x = DECAY * w.x + OMD * ccount * em.x;
            nw.y = DECAY * w.y + OMD * ccount * em.y;
            nw.z = DECAY * w.z + OMD * ccount * em.z;
            nw.w = DECAY * w.w + OMD * ccount * em.w;
            __builtin_nontemporal_store(
                nw, reinterpret_cast<f4*>(new_ema_w_out) + e);
            const float inv = 1.0f / cs;
            f4 nb;
            nb.x = nw.x * inv;
            nb.y = nw.y * inv;
            nb.z = nw.z * inv;
            nb.w = nw.w * inv;
            __builtin_nontemporal_store(
                nb, reinterpret_cast<f4*>(new_emb_out) + e);
        }
    }
}

extern "C" void kernel_launch(void* const* d_in, const int* in_sizes, int n_in,
                              void* d_out, int out_size, void* d_ws, size_t ws_size,
                              hipStream_t stream) {
    const int*   idx   = (const int*)d_in[0];
    const float* emb   = (const float*)d_in[1];
    const float* ecs   = (const float*)d_in[2];
    const float* ema_w = (const float*)d_in[3];

    float* out       = (float*)d_out;
    float* z_q       = out;                                  // [B,S,D]
    float* new_emb   = z_q + (size_t)B_ * S_ * D_;           // [S,K,D]
    float* new_ecs   = new_emb + (size_t)S_ * K_ * D_;       // [S,K]
    float* new_ema_w = new_ecs + (size_t)S_ * K_;            // [S,K,D]

    fused_kernel<<<4096, 256, 0, stream>>>(
        idx, emb, ecs, ema_w, z_q, new_ecs, new_ema_w, new_emb);
}

// Round 11
// 34.298 us; speedup vs baseline: 1.7165x; 1.7165x over previous
//
#include <hip/hip_runtime.h>

// Problem constants
#define B_ 4096
#define S_ 32
#define K_ 1024
#define D_ 128
constexpr float DECAY = 0.99f;
constexpr float OMD   = 0.01f;     // 1 - decay
constexpr float EPS   = 1e-5f;

typedef float f4 __attribute__((ext_vector_type(4)));
typedef int   i4 __attribute__((ext_vector_type(4)));

// ws layout: [0, S_*K_) int counts ; then S_ floats n[s]

// K1: full per-s histogram + n[s]. 32 blocks x 1024 threads, one block per s.
// Coalesced int4 scan of the whole idx (512 KB, L2/L3-hot under replay):
// flat element (i*1024+t)*4+j has col 4*(t&7)+j, so lane bins v[s&3] iff
// (t&7)==(s>>2) -- full-width coalesced loads, 1/8 of lanes do LDS atomics.
// No global atomics, no zero-init kernel, and n[s] computed here once:
// n = DECAY*rowsum(ecs[s]) + OMD*B  (sum_k counts[s,k] == B exactly).
__global__ void __launch_bounds__(1024)
hist_kernel(const int* __restrict__ idx,
            const float* __restrict__ ecs_in,
            int* __restrict__ counts,
            float* __restrict__ n_arr) {
    const int s = blockIdx.x;
    const int t = threadIdx.x;
    __shared__ int   hist[K_];
    __shared__ float red[16];
    hist[t] = 0;
    __syncthreads();

    const bool mine = (t & 7) == (s >> 2);
    const int  jsel = s & 3;
    const i4* src = reinterpret_cast<const i4*>(idx);
#pragma unroll 8
    for (int i = 0; i < 32; ++i) {
        const i4 v = src[i * 1024 + t];           // coalesced 16B/lane
        if (mine) atomicAdd(&hist[v[jsel]], 1);   // elem at col s
    }

    // n[s] rowsum: 1024 floats, 1/thread; wave butterfly + 16-wave LDS combine.
    float local = ecs_in[s * K_ + t];
#pragma unroll
    for (int off = 1; off < 64; off <<= 1) local += __shfl_xor(local, off);
    if ((t & 63) == 0) red[t >> 6] = local;
    __syncthreads();                              // publishes hist + red
    counts[s * K_ + t] = hist[t];                 // coalesced 4KB row
    if (t == 0) {
        float sum = 0.0f;
#pragma unroll
        for (int i = 0; i < 16; ++i) sum += red[i];
        n_arr[s] = DECAY * sum + OMD * (float)B_;
    }
}

// K2: single big kernel, 4096 blocks x 256, role-split by blockIdx bit 3:
//   role 0 (2048): z_q gather (write-heavy, NT stores)
//   role 1 (2048): fused EMA/Laplace elementwise (reads counts/n_arr scalars)
// sub%8 == blockIdx%8 keeps s%8 == XCD (round-robin %8): each s's 512KB emb
// slice pinned in one XCD's L2 for both roles. NT stores for the 101MB of
// write-once outputs (R9 A/B: NT beats plain by 2.5us, write-allocate).
__global__ void __launch_bounds__(256)
main_kernel(const int* __restrict__ idx,
            const float* __restrict__ emb,
            const float* __restrict__ ecs_in,
            const float* __restrict__ ema_w,
            const int* __restrict__ counts,
            const float* __restrict__ n_arr,
            float* __restrict__ z_q,
            float* __restrict__ new_ecs_out,
            float* __restrict__ new_ema_w_out,
            float* __restrict__ new_emb_out) {
    const int role = (blockIdx.x >> 3) & 1;
    const int sub  = (int)(((blockIdx.x >> 4) << 3) | (blockIdx.x & 7)); // [0,2048)
    const int t    = threadIdx.x;
    const int s    = sub & (S_ - 1);

    if (role == 0) {
        // ---- Gather: 64 rows/block, 8 idx prefetched -> 8 gathers in flight.
        const int chunk = sub >> 5;          // [0, 64)
        const int g     = t >> 5;            // row group 0..7
        const int lane  = t & 31;
        int kk[8];
#pragma unroll
        for (int it = 0; it < 8; ++it) {
            const int b = chunk * 64 + it * 8 + g;
            kk[it] = idx[b * S_ + s];        // broadcast within 32-lane group
        }
#pragma unroll
        for (int it = 0; it < 8; ++it) {
            const int b = chunk * 64 + it * 8 + g;
            const f4 val =
                reinterpret_cast<const f4*>(emb)[((size_t)s * K_ + kk[it]) * 32 + lane];
            __builtin_nontemporal_store(
                val, reinterpret_cast<f4*>(z_q) + ((size_t)b * S_ + s) * 32 + lane);
        }
    } else {
        // ---- EMA: k-chunk c of 16 bins for state s; pure elementwise.
        const int c     = sub >> 5;          // [0, 64)
        const int kbase = c * 16;
        const float n = n_arr[s];
        const float denom_inv = 1.0f / (n + (float)K_ * EPS);
        const size_t base = ((size_t)s * K_ + kbase) * 32;   // f4 base
#pragma unroll
        for (int it = 0; it < 2; ++it) {
            const int    off = it * 256 + t;
            const size_t e   = base + off;   // global f4 index
            const int    sk  = (int)(e >> 5);
            const float ccount = (float)counts[sk];   // L2-hot broadcast
            const float ne = DECAY * ecs_in[sk] + OMD * ccount;
            const float cs = (ne + EPS) * denom_inv * n;
            if ((off & 31) == 0) new_ecs_out[sk] = ne;

            const f4 w  = reinterpret_cast<const f4*>(ema_w)[e];
            const f4 em = reinterpret_cast<const f4*>(emb)[e];
            f4 nw;
            nw.x = DECAY * w.x + OMD * ccount * em.x;
            nw.y = DECAY * w.y + OMD * ccount * em.y;
            nw.z = DECAY * w.z + OMD * ccount * em.z;
            nw.w = DECAY * w.w + OMD * ccount * em.w;
            __builtin_nontemporal_store(
                nw, reinterpret_cast<f4*>(new_ema_w_out) + e);
            const float inv = 1.0f / cs;
            f4 nb;
            nb.x = nw.x * inv;
            nb.y = nw.y * inv;
            nb.z = nw.z * inv;
            nb.w = nw.w * inv;
            __builtin_nontemporal_store(
                nb, reinterpret_cast<f4*>(new_emb_out) + e);
        }
    }
}

extern "C" void kernel_launch(void* const* d_in, const int* in_sizes, int n_in,
                              void* d_out, int out_size, void* d_ws, size_t ws_size,
                              hipStream_t stream) {
    const int*   idx   = (const int*)d_in[0];
    const float* emb   = (const float*)d_in[1];
    const float* ecs   = (const float*)d_in[2];
    const float* ema_w = (const float*)d_in[3];

    float* out       = (float*)d_out;
    float* z_q       = out;                                  // [B,S,D]
    float* new_emb   = z_q + (size_t)B_ * S_ * D_;           // [S,K,D]
    float* new_ecs   = new_emb + (size_t)S_ * K_ * D_;       // [S,K]
    float* new_ema_w = new_ecs + (size_t)S_ * K_;            // [S,K,D]

    int*   counts = (int*)d_ws;                              // S*K ints (128 KB)
    float* n_arr  = (float*)d_ws + (size_t)S_ * K_;          // S floats

    hist_kernel<<<S_, 1024, 0, stream>>>(idx, ecs, counts, n_arr);
    main_kernel<<<4096, 256, 0, stream>>>(
        idx, emb, ecs, ema_w, counts, n_arr, z_q, new_ecs, new_ema_w, new_emb);
}

// Round 12
// 30.034 us; speedup vs baseline: 1.9602x; 1.1420x over previous
//
#include <hip/hip_runtime.h>

// Problem constants
#define B_ 4096
#define S_ 32
#define K_ 1024
#define D_ 128
constexpr float DECAY = 0.99f;
constexpr float OMD   = 0.01f;     // 1 - decay
constexpr float EPS   = 1e-5f;

typedef float          f4  __attribute__((ext_vector_type(4)));
typedef int            i4  __attribute__((ext_vector_type(4)));
typedef unsigned short u16;
typedef u16            us8 __attribute__((ext_vector_type(8)));

// ============ Fast path: 2 kernels, no global atomics, no init ============
// ws layout: [0, B_*S_) u16 idx_T  (256 KB), transposed indices idx_T[s][b].
//
// Best structure (R8, 30.4 us). Verdicts from A/B rounds:
//  - NT stores beat plain stores by 2.5 us (R9: write-allocate cost).
//  - Sequential kernels beat role-mixed fusion (R10/R11: during the gather
//    phase L2 holds ONLY emb slices; mixing streams ema_w through L2 and
//    evicts the pinned gather working set).
//  - Cooperative single-kernel is 9x worse (R4: latency-bound, grid.sync
//    L2 flushes).

// Kernel A: z_q gather + idx transpose. 2048 blocks x 256 threads.
// s-major mapping (s = blockIdx&31): all 64 blocks of a given s land on XCD
// s%8 (round-robin dispatch), pinning that s's 512KB emb slice in one L2
// (4 slices = 2MB per XCD). 64 rows/block; 8 idx loads prefetched into
// registers -> 8 independent gather loads in flight.
__global__ void __launch_bounds__(256)
gather_t_kernel(const int* __restrict__ idx,
                const float* __restrict__ emb,
                float* __restrict__ z_q,
                u16* __restrict__ idx_t) {
    const int s     = blockIdx.x & (S_ - 1);
    const int chunk = blockIdx.x >> 5;          // [0, 64)
    const int g     = threadIdx.x >> 5;         // row group 0..7
    const int lane  = threadIdx.x & 31;

    int kk[8];
#pragma unroll
    for (int it = 0; it < 8; ++it) {
        const int b = chunk * 64 + it * 8 + g;
        kk[it] = idx[b * S_ + s];               // broadcast within 32-lane group
    }
#pragma unroll
    for (int it = 0; it < 8; ++it) {
        const int b = chunk * 64 + it * 8 + g;
        if (lane == 0)                           // direct u16 transpose store
            idx_t[(size_t)s * B_ + b] = (u16)kk[it];
        const f4 val =
            reinterpret_cast<const f4*>(emb)[((size_t)s * K_ + kk[it]) * 32 + lane];
        __builtin_nontemporal_store(
            val, reinterpret_cast<f4*>(z_q) + ((size_t)b * S_ + s) * 32 + lane);
    }
}

// Kernel B: LDS histogram + n[s] + fused EMA/Laplace. 2048 blocks x 256.
// Block i: s = i&31 (XCD-aligned with kernel A's warm emb slice), k-chunk
// c = i>>5 of 16 bins. Scans its s-column of idx_T (8KB, coalesced) into a
// 16-bin LDS histogram; n from closed form n = DECAY*rowsum(ecs[s]) + OMD*B
// (sum_k counts == B exactly). 2 f4/thread EMA tail.
__global__ void __launch_bounds__(256)
ema_hist_kernel(const u16* __restrict__ idx_t,
                const float* __restrict__ emb,
                const float* __restrict__ ecs_in,
                const float* __restrict__ ema_w,
                float* __restrict__ new_ecs_out,
                float* __restrict__ new_ema_w_out,
                float* __restrict__ new_emb_out) {
    const int s     = blockIdx.x & (S_ - 1);
    const int c     = blockIdx.x >> 5;          // k-chunk [0, 64)
    const int t     = threadIdx.x;
    const int kbase = c * 16;

    __shared__ int   hist[16];
    __shared__ float red[4];
    __shared__ float n_sh;
    if (t < 16) hist[t] = 0;
    __syncthreads();

    // Histogram scan: 4096 u16 = 512 ushort8; 2 per thread, coalesced.
    const us8* col = reinterpret_cast<const us8*>(idx_t + (size_t)s * B_);
#pragma unroll
    for (int it = 0; it < 2; ++it) {
        const us8 v = col[it * 256 + t];
#pragma unroll
        for (int j = 0; j < 8; ++j) {
            const unsigned u = (unsigned)v[j] - (unsigned)kbase;
            if (u < 16u) atomicAdd(&hist[u], 1);
        }
    }

    // n[s] via closed form.
    const f4 v = reinterpret_cast<const f4*>(ecs_in + s * K_)[t];
    float local = v.x + v.y + v.z + v.w;
#pragma unroll
    for (int off = 1; off < 64; off <<= 1) local += __shfl_xor(local, off);
    if ((t & 63) == 0) red[t >> 6] = local;
    __syncthreads();                 // also publishes hist atomics
    if (t == 0)
        n_sh = DECAY * (red[0] + red[1] + red[2] + red[3]) + OMD * (float)B_;
    __syncthreads();
    const float n = n_sh;
    const float denom_inv = 1.0f / (n + (float)K_ * EPS);

    // Fused EMA elementwise: 512 f4 per block (16 bins x 32 f4).
    const size_t base = ((size_t)s * K_ + kbase) * 32;   // f4 base
#pragma unroll
    for (int it = 0; it < 2; ++it) {
        const int    off = it * 256 + t;
        const int    ub  = off >> 5;             // local bin [0, 16)
        const size_t e   = base + off;           // global f4 index
        const int    sk  = (int)(e >> 5);
        const float ccount = (float)hist[ub];
        const float ne = DECAY * ecs_in[sk] + OMD * ccount;
        const float cs = (ne + EPS) * denom_inv * n;
        if ((off & 31) == 0) new_ecs_out[sk] = ne;

        const f4 w  = reinterpret_cast<const f4*>(ema_w)[e];
        const f4 em = reinterpret_cast<const f4*>(emb)[e];
        f4 nw;
        nw.x = DECAY * w.x + OMD * ccount * em.x;
        nw.y = DECAY * w.y + OMD * ccount * em.y;
        nw.z = DECAY * w.z + OMD * ccount * em.z;
        nw.w = DECAY * w.w + OMD * ccount * em.w;
        __builtin_nontemporal_store(nw, reinterpret_cast<f4*>(new_ema_w_out) + e);
        const float inv = 1.0f / cs;
        f4 nb;
        nb.x = nw.x * inv;
        nb.y = nw.y * inv;
        nb.z = nw.z * inv;
        nb.w = nw.w * inv;
        __builtin_nontemporal_store(nb, reinterpret_cast<f4*>(new_emb_out) + e);
    }
}

// ============ Fallback path (proven R6 structure), used if ws < 256 KB ============

__global__ void __launch_bounds__(256)
init_kernel(const float* __restrict__ ecs_in,
            int* __restrict__ counts,
            float* __restrict__ n_out) {
    const int s = blockIdx.x;
    const int t = threadIdx.x;
    reinterpret_cast<i4*>(counts + s * K_)[t] = i4{0, 0, 0, 0};
    const f4 v = reinterpret_cast<const f4*>(ecs_in + s * K_)[t];
    float local = v.x + v.y + v.z + v.w;
#pragma unroll
    for (int off = 1; off < 64; off <<= 1) local += __shfl_xor(local, off);
    __shared__ float red[4];
    if ((t & 63) == 0) red[t >> 6] = local;
    __syncthreads();
    if (t == 0)
        n_out[s] = DECAY * (red[0] + red[1] + red[2] + red[3]) + OMD * (float)B_;
}

__global__ void __launch_bounds__(256)
gather_hist_kernel(const int* __restrict__ idx,
                   const float* __restrict__ emb,
                   float* __restrict__ z_q,
                   int* __restrict__ counts) {
    const int s     = blockIdx.x & (S_ - 1);
    const int chunk = blockIdx.x >> 5;
    const int g     = threadIdx.x >> 5;
    const int lane  = threadIdx.x & 31;
    const int b     = chunk * 8 + g;
    const int row   = b * S_ + s;
    const int k     = idx[row];
    if (lane == 0) atomicAdd(&counts[s * K_ + k], 1);
    const f4 val =
        reinterpret_cast<const f4*>(emb)[((size_t)s * K_ + k) * 32 + lane];
    __builtin_nontemporal_store(
        val, reinterpret_cast<f4*>(z_q) + (size_t)row * 32 + lane);
}

__global__ void __launch_bounds__(256)
ema_kernel(const float* __restrict__ ema_w,
           const float* __restrict__ emb,
           const float* __restrict__ ecs_in,
           const int* __restrict__ counts,
           const float* __restrict__ n_arr,
           float* __restrict__ new_ecs_out,
           float* __restrict__ new_ema_w_out,
           float* __restrict__ new_emb_out) {
    const int i = blockIdx.x;
    const int s = i & (S_ - 1);
    const int c = i >> 5;
    const size_t base = ((size_t)s * K_ + c * 32) * 32;
    const float n = n_arr[s];
    const float denom_inv = 1.0f / (n + (float)K_ * EPS);
#pragma unroll
    for (int it = 0; it < 4; ++it) {
        const size_t e = base + it * 256 + threadIdx.x;
        const int sk = (int)(e >> 5);
        const float ccount = (float)counts[sk];
        const float ne = DECAY * ecs_in[sk] + OMD * ccount;
        const float cs = (ne + EPS) * denom_inv * n;
        if ((e & 31) == 0) new_ecs_out[sk] = ne;
        const f4 w  = reinterpret_cast<const f4*>(ema_w)[e];
        const f4 em = reinterpret_cast<const f4*>(emb)[e];
        f4 nw;
        nw.x = DECAY * w.x + OMD * ccount * em.x;
        nw.y = DECAY * w.y + OMD * ccount * em.y;
        nw.z = DECAY * w.z + OMD * ccount * em.z;
        nw.w = DECAY * w.w + OMD * ccount * em.w;
        __builtin_nontemporal_store(nw, reinterpret_cast<f4*>(new_ema_w_out) + e);
        const float inv = 1.0f / cs;
        f4 nb;
        nb.x = nw.x * inv;
        nb.y = nw.y * inv;
        nb.z = nw.z * inv;
        nb.w = nw.w * inv;
        __builtin_nontemporal_store(nb, reinterpret_cast<f4*>(new_emb_out) + e);
    }
}

extern "C" void kernel_launch(void* const* d_in, const int* in_sizes, int n_in,
                              void* d_out, int out_size, void* d_ws, size_t ws_size,
                              hipStream_t stream) {
    const int*   idx   = (const int*)d_in[0];
    const float* emb   = (const float*)d_in[1];
    const float* ecs   = (const float*)d_in[2];
    const float* ema_w = (const float*)d_in[3];

    float* out       = (float*)d_out;
    float* z_q       = out;                                  // [B,S,D]
    float* new_emb   = z_q + (size_t)B_ * S_ * D_;           // [S,K,D]
    float* new_ecs   = new_emb + (size_t)S_ * K_ * D_;       // [S,K]
    float* new_ema_w = new_ecs + (size_t)S_ * K_;            // [S,K,D]

    if (ws_size >= (size_t)B_ * S_ * sizeof(u16)) {
        // Fast path: 2 kernels, idx_T in ws.
        u16* idx_t = (u16*)d_ws;
        gather_t_kernel<<<2048, 256, 0, stream>>>(idx, emb, z_q, idx_t);
        ema_hist_kernel<<<2048, 256, 0, stream>>>(
            idx_t, emb, ecs, ema_w, new_ecs, new_ema_w, new_emb);
    } else {
        // Fallback: proven R6 3-kernel path (counts + n in ws, 128.2 KB).
        int*   counts = (int*)d_ws;
        float* n_arr  = (float*)d_ws + (size_t)S_ * K_;
        init_kernel<<<S_, 256, 0, stream>>>(ecs, counts, n_arr);
        gather_hist_kernel<<<(B_ * S_) / 8, 256, 0, stream>>>(idx, emb, z_q, counts);
        ema_kernel<<<1024, 256, 0, stream>>>(
            ema_w, emb, ecs, counts, n_arr, new_ecs, new_ema_w, new_emb);
    }
}